// Round 14
// baseline (79.554 us; speedup 1.0000x reference)
//
#include <hip/hip_runtime.h>
#include <math.h>

#define NUM_ENT 10000
#define NUM_REL 230
#define R2      460
#define S_DIM   96
#define T_DIM   32
#define DIM     128
#define N_NBR   32768
#define Q_ENT   4096
#define E_EDGE  32768
#define B_TRI   1024
#define BN_EPS  1e-5f
#define CHUNK   64

typedef __attribute__((ext_vector_type(8))) short bf16x8;
typedef __attribute__((ext_vector_type(4))) float f32x4;

// f32 -> bf16 round-to-nearest-even
__device__ __forceinline__ unsigned short f2bf(float f) {
    unsigned int u = __float_as_uint(f);
    u = (u + 0x7FFFu + ((u >> 16) & 1u)) >> 16;
    return (unsigned short)u;
}
__device__ __forceinline__ float bf2f(unsigned short us) {
    return __uint_as_float((unsigned int)us << 16);
}

// X LDS swizzle (ushort units): breaks the 256B row stride for A-frag b128
// reads. XOR bits >=3 keep 4-ushort groups contiguous (8B stores ok).
__device__ __forceinline__ int XIDX(int m, int d) {
    return (m * DIM + d) ^ ((m & 7) << 3);
}

// ---------------------------------------------------------------------------
// K0: zero psum(524288) + pcnt(4096) + hist_rel(460) + histE(460)
//     = 529304 ints = 132326 int4 (region is contiguous in ws)
// ---------------------------------------------------------------------------
__global__ void k_zero(int* __restrict__ p, int n4) {
    int i = blockIdx.x * blockDim.x + threadIdx.x;
    if (i < n4) ((int4*)p)[i] = make_int4(0, 0, 0, 0);
}

// ---------------------------------------------------------------------------
// K1: blocks [0,460): W[r] f32 -> bf16 in per-lane MFMA fragment order.
//   Wfrag ushort offset: ((kk*4+wv)*2+h)*512 + lane*8 + j holds
//   bf16(W[r][32*kk + 8*(lane>>4) + j][32*wv + 16*h + (lane&15)]).
// blocks [460,588): tickets: neighbor rank within its relation bucket,
//   edge rank within its source-relation bucket, plus per-query edge count.
// ---------------------------------------------------------------------------
__global__ __launch_bounds__(256, 2) void k_front(
    const float* __restrict__ W, unsigned short* __restrict__ Wfrag,
    const int* __restrict__ rel, const int* __restrict__ psrc,
    const int* __restrict__ pdst,
    int* __restrict__ hist_rel, int* __restrict__ histE,
    int* __restrict__ pcnt,
    int* __restrict__ ticket_n, int* __restrict__ ticket_e)
{
    const int t = threadIdx.x;
    if (blockIdx.x >= R2) {
        const int i = (blockIdx.x - R2) * 256 + t;
        if (i < N_NBR) ticket_n[i] = atomicAdd(&hist_rel[rel[i]], 1);
        if (i < E_EDGE) {
            const int s = psrc[i];
            ticket_e[i] = atomicAdd(&histE[rel[s]], 1);
            atomicAdd(&pcnt[pdst[i]], 1);
        }
        return;
    }
    const int r = blockIdx.x;
    __shared__ float Wl[DIM * DIM];   // 64 KB
    {
        const float4* Wg = (const float4*)(W + (size_t)r * DIM * DIM);
        float4* Wl4 = (float4*)Wl;
        #pragma unroll
        for (int i = 0; i < 16; ++i)
            Wl4[t + i * 256] = Wg[t + i * 256];
    }
    __syncthreads();
    unsigned short* dst = Wfrag + (size_t)r * DIM * DIM;
    #pragma unroll
    for (int it = 0; it < 8; ++it) {
        const int id = t + it * 256;            // 0..2047
        const int lane = id & 63;
        const int h    = (id >> 6) & 1;
        const int wv   = (id >> 7) & 3;
        const int kk   = (id >> 9) & 3;
        const int n  = 32 * wv + 16 * h + (lane & 15);
        const int kb = 32 * kk + 8 * (lane >> 4);
        ushort4 lo, hi;
        lo.x = f2bf(Wl[(kb + 0) * DIM + n]);
        lo.y = f2bf(Wl[(kb + 1) * DIM + n]);
        lo.z = f2bf(Wl[(kb + 2) * DIM + n]);
        lo.w = f2bf(Wl[(kb + 3) * DIM + n]);
        hi.x = f2bf(Wl[(kb + 4) * DIM + n]);
        hi.y = f2bf(Wl[(kb + 5) * DIM + n]);
        hi.z = f2bf(Wl[(kb + 6) * DIM + n]);
        hi.w = f2bf(Wl[(kb + 7) * DIM + n]);
        *(ushort4*)&dst[id * 8]     = lo;
        *(ushort4*)&dst[id * 8 + 4] = hi;
    }
}

// ---------------------------------------------------------------------------
// K2: place. Every block redoes BOTH 460-bin scans in LDS (cheap, no
// cross-block dependency), then scatters using offset[bucket] + ticket.
// Block 0 additionally publishes offsets[461] and eoff[461] for k_matvec.
// ---------------------------------------------------------------------------
__global__ __launch_bounds__(256) void k_place(
    const int* __restrict__ rel, const int* __restrict__ psrc,
    const int* __restrict__ pdst,
    const int* __restrict__ hist_rel, const int* __restrict__ histE,
    const int* __restrict__ ticket_n, const int* __restrict__ ticket_e,
    int* __restrict__ offsets, int* __restrict__ eoff,
    int* __restrict__ order, int* __restrict__ rankpack,
    int* __restrict__ epack)
{
    __shared__ int hA[512], hB[512], part[256];
    const int t = threadIdx.x;
    const int b = blockIdx.x;
    hA[t]       = (t < R2) ? hist_rel[t] : 0;
    hA[t + 256] = (t + 256 < R2) ? hist_rel[t + 256] : 0;
    hB[t]       = (t < R2) ? histE[t] : 0;
    hB[t + 256] = (t + 256 < R2) ? histE[t + 256] : 0;
    __syncthreads();

    // ---- scan A (rel buckets): thread owns bins 2t, 2t+1
    const int a0 = hA[2 * t], a1 = hA[2 * t + 1];
    part[t] = a0 + a1;
    __syncthreads();
    for (int off = 1; off < 256; off <<= 1) {
        int v = (t >= off) ? part[t - off] : 0;
        __syncthreads();
        part[t] += v;
        __syncthreads();
    }
    {
        const int ex = t ? part[t - 1] : 0;
        hA[2 * t] = ex; hA[2 * t + 1] = ex + a0;
        if (b == 0) {
            if (2 * t < R2)     offsets[2 * t]     = ex;
            if (2 * t + 1 < R2) offsets[2 * t + 1] = ex + a0;
            if (t == 255)       offsets[R2]        = part[255];
        }
    }
    __syncthreads();

    // ---- scan B (edge source-relation buckets)
    const int b0 = hB[2 * t], b1 = hB[2 * t + 1];
    part[t] = b0 + b1;
    __syncthreads();
    for (int off = 1; off < 256; off <<= 1) {
        int v = (t >= off) ? part[t - off] : 0;
        __syncthreads();
        part[t] += v;
        __syncthreads();
    }
    {
        const int ex = t ? part[t - 1] : 0;
        hB[2 * t] = ex; hB[2 * t + 1] = ex + b0;
        if (b == 0) {
            if (2 * t < R2)     eoff[2 * t]     = ex;
            if (2 * t + 1 < R2) eoff[2 * t + 1] = ex + b0;
            if (t == 255)       eoff[R2]        = part[255];
        }
    }
    __syncthreads();

    // ---- scatter
    const int i = b * 256 + t;
    if (i < N_NBR) {
        const int r = rel[i];
        const int pos = hA[r] + ticket_n[i];
        order[pos] = i;
        rankpack[i] = pos;
    }
    if (i < E_EDGE) {
        const int s = psrc[i];
        const int kr = rel[s];
        const int epos = hB[kr] + ticket_e[i];
        epack[epos] = s | (pdst[i] << 15);   // psrc 15b | pdst 12b
    }
}

// ---------------------------------------------------------------------------
// K3: MFMA matvec + BN + FUSED POOL. One block (512 thr = 8 waves) per
// relation; two 64-row chunks in flight (half = wid>>2). After the BN fold,
// scale/shift stay in LDS; the block walks its own edge segment (sorted by
// source relation), re-reads its L2-hot bf16 z rows, applies affine+ReLU,
// and atomic-adds into psum[q]. No scsh buffer, no pool kernel.
// ---------------------------------------------------------------------------
__global__ __launch_bounds__(512, 4) void k_matvec(
    const int* __restrict__ order, const int* __restrict__ offsets,
    const int* __restrict__ eoff, const int* __restrict__ epack,
    const int* __restrict__ rankpack,
    const int* __restrict__ nbr,
    const float* __restrict__ years, const float* __restrict__ months, const float* __restrict__ days,
    const float* __restrict__ ent,
    const float* __restrict__ yf, const float* __restrict__ yp, const float* __restrict__ ya,
    const float* __restrict__ mf, const float* __restrict__ mp, const float* __restrict__ ma,
    const float* __restrict__ df, const float* __restrict__ dp, const float* __restrict__ da,
    const unsigned short* __restrict__ Wfrag, const float* __restrict__ bias,
    const float* __restrict__ gamma, const float* __restrict__ beta,
    unsigned short* __restrict__ z_s, float* __restrict__ psum)
{
    const int r     = blockIdx.x;
    const int start = offsets[r];
    const int cnt   = offsets[r + 1] - start;

    __shared__ __align__(16) unsigned short Xl[2][CHUNK * DIM];  // 32 KB
    __shared__ int s_ord[2][CHUNK];
    __shared__ int s_ni[2][CHUNK];
    __shared__ float bnred[8][2][16][2];   // [wid][nt][l15][sum|sq]
    __shared__ float scl[DIM], shf[DIM];

    const int t    = threadIdx.x;
    const int wid  = t >> 6;        // 0..7
    const int half = wid >> 2;      // 0,1 : which chunk of the pair
    const int wv   = wid & 3;       // column group
    const int lane = t & 63;
    const int l15  = lane & 15;
    const int g    = lane >> 4;

    const int nn0 = 32 * wv + l15;
    const int nn1 = nn0 + 16;
    const float bv0 = bias[r * DIM + nn0];
    const float bv1 = bias[r * DIM + nn1];

    float lsum0 = 0.f, lsq0 = 0.f, lsum1 = 0.f, lsq1 = 0.f;
    const unsigned short* Wr = Wfrag + (size_t)r * DIM * DIM;

    for (int cbase = 0; cbase < cnt; cbase += 2 * CHUNK) {
        const int hbase = cbase + half * CHUNK;
        const int mcnt  = min(CHUNK, max(0, cnt - hbase));

        if (t < 2 * CHUNK) {
            const int hh = t >> 6;   // half being staged
            const int m  = t & 63;
            const int gb = cbase + hh * CHUNK;
            int o = -1, ni = 0;
            if (gb + m < cnt) { o = order[start + gb + m]; ni = nbr[o]; }
            s_ord[hh][m] = o;
            s_ni[hh][m]  = ni;
        }
        __syncthreads();

        // ---- gather X for this half (256 threads): 4 thr/row
        if (mcnt > 0) {
            const int lt = t & 255;
            const int m = lt >> 2, s = lt & 3;
            const int ni = s_ni[half][m];
            const bool vm = (m < mcnt);
            #pragma unroll
            for (int kk = 0; kk < 6; ++kk) {
                const int d = 4 * (s + 4 * kk);
                float4 e = *(const float4*)(ent + (size_t)ni * S_DIM + d);
                ushort4 b;
                b.x = vm ? f2bf(e.x) : 0; b.y = vm ? f2bf(e.y) : 0;
                b.z = vm ? f2bf(e.z) : 0; b.w = vm ? f2bf(e.w) : 0;
                *(ushort4*)&Xl[half][XIDX(m, d)] = b;
            }
            const int o = s_ord[half][m] < 0 ? 0 : s_ord[half][m];
            const float yr = years[o], mo = months[o], dy = days[o];
            #pragma unroll
            for (int hh = 0; hh < 2; ++hh) {
                const int j0 = s * 8 + hh * 4;
                const size_t tb = (size_t)ni * T_DIM + j0;
                const float4 vyf = *(const float4*)(yf + tb), vyp = *(const float4*)(yp + tb), vya = *(const float4*)(ya + tb);
                const float4 vmf = *(const float4*)(mf + tb), vmp = *(const float4*)(mp + tb), vma = *(const float4*)(ma + tb);
                const float4 vdf = *(const float4*)(df + tb), vdp = *(const float4*)(dp + tb), vda = *(const float4*)(da + tb);
                ushort4 b;
                #pragma unroll
                for (int j = 0; j < 4; ++j) {
                    const float fy = ((const float*)&vyf)[j] * yr + ((const float*)&vyp)[j];
                    const float fm = ((const float*)&vmf)[j] * mo + ((const float*)&vmp)[j];
                    const float fd = ((const float*)&vdf)[j] * dy + ((const float*)&vdp)[j];
                    float v = ((const float*)&vya)[j] * sinf(fy)
                            + ((const float*)&vma)[j] * sinf(fm)
                            + ((const float*)&vda)[j] * sinf(fd);
                    ((unsigned short*)&b)[j] = vm ? f2bf(v) : 0;
                }
                *(ushort4*)&Xl[half][XIDX(m, S_DIM + j0)] = b;
            }
        }
        __syncthreads();

        // ---- MFMA + epilogue for this half
        if (mcnt > 0) {
            f32x4 acc[4][2];
            #pragma unroll
            for (int i = 0; i < 4; ++i)
                #pragma unroll
                for (int j = 0; j < 2; ++j) acc[i][j] = (f32x4)0.f;

            #pragma unroll
            for (int kk = 0; kk < 4; ++kk) {
                const int k0 = kk * 32;
                bf16x8 a[4];
                #pragma unroll
                for (int mt = 0; mt < 4; ++mt)
                    a[mt] = *(const bf16x8*)&Xl[half][XIDX(16 * mt + l15, k0 + 8 * g)];
                const bf16x8 b0 = *(const bf16x8*)&Wr[(size_t)((kk * 4 + wv) * 2 + 0) * 512 + lane * 8];
                const bf16x8 b1 = *(const bf16x8*)&Wr[(size_t)((kk * 4 + wv) * 2 + 1) * 512 + lane * 8];
                #pragma unroll
                for (int mt = 0; mt < 4; ++mt) {
                    acc[mt][0] = __builtin_amdgcn_mfma_f32_16x16x32_bf16(a[mt], b0, acc[mt][0], 0, 0, 0);
                    acc[mt][1] = __builtin_amdgcn_mfma_f32_16x16x32_bf16(a[mt], b1, acc[mt][1], 0, 0, 0);
                }
            }

            #pragma unroll
            for (int mt = 0; mt < 4; ++mt) {
                #pragma unroll
                for (int reg = 0; reg < 4; ++reg) {
                    const int ml = 16 * mt + 4 * g + reg;
                    if (ml < mcnt) {
                        const float v0 = acc[mt][0][reg] + bv0;
                        const float v1 = acc[mt][1][reg] + bv1;
                        const size_t row = (size_t)(start + hbase + ml) * DIM;
                        z_s[row + nn0] = f2bf(v0);
                        z_s[row + nn1] = f2bf(v1);
                        lsum0 += v0; lsq0 += v0 * v0;
                        lsum1 += v1; lsq1 += v1 * v1;
                    }
                }
            }
        }
        __syncthreads();
    }

    // ---- BN fold: intra-wave (over g), cross-half via LDS -> scl/shf LDS
    lsum0 += __shfl_xor(lsum0, 16); lsum0 += __shfl_xor(lsum0, 32);
    lsq0  += __shfl_xor(lsq0, 16);  lsq0  += __shfl_xor(lsq0, 32);
    lsum1 += __shfl_xor(lsum1, 16); lsum1 += __shfl_xor(lsum1, 32);
    lsq1  += __shfl_xor(lsq1, 16);  lsq1  += __shfl_xor(lsq1, 32);
    if (g == 0) {
        bnred[wid][0][l15][0] = lsum0; bnred[wid][0][l15][1] = lsq0;
        bnred[wid][1][l15][0] = lsum1; bnred[wid][1][l15][1] = lsq1;
    }
    __syncthreads();
    if (half == 0 && g == 0) {
        #pragma unroll
        for (int nt = 0; nt < 2; ++nt) {
            const int col = 32 * wv + 16 * nt + l15;
            const float s = bnred[wid][nt][l15][0] + bnred[wid + 4][nt][l15][0];
            const float q = bnred[wid][nt][l15][1] + bnred[wid + 4][nt][l15][1];
            float sc = 1.f, sh = 0.f;
            if (cnt > 1) {
                const float mean = s / (float)cnt;
                const float var  = fmaxf(q / (float)cnt - mean * mean, 0.f);
                const int gi = r * DIM + col;
                sc = gamma[gi] * rsqrtf(var + BN_EPS);
                sh = beta[gi] - mean * sc;
            }
            scl[col] = sc;
            shf[col] = sh;
        }
    }
    __syncthreads();

    // ---- FUSED POOL: walk this relation's edge segment; z rows L2-hot.
    {
        const int e0 = eoff[r], e1 = eoff[r + 1];
        const int grp = t >> 7;      // 4 edges concurrently (128 thr each)
        const int d   = t & 127;
        const float psc = scl[d], psh = shf[d];
        for (int e = e0 + grp; e < e1; e += 4) {
            const int pk  = epack[e];
            const int s   = pk & 0x7FFF;
            const int q   = pk >> 15;
            const int row = rankpack[s];
            const float v = fmaxf(bf2f(z_s[(size_t)row * DIM + d]) * psc + psh, 0.f);
            atomicAdd(&psum[(size_t)q * DIM + d], v);
        }
    }
}

// ---------------------------------------------------------------------------
// K4: TransE scoring; emb computed on the fly from psum/pcnt.
// ---------------------------------------------------------------------------
__global__ void k_score(const int* __restrict__ head, const int* __restrict__ tail,
                        const int* __restrict__ rels,
                        const float* __restrict__ psum, const int* __restrict__ pcnt,
                        const float* __restrict__ rel_embs,
                        float* __restrict__ out)
{
    const int b = blockIdx.x;
    const int d = threadIdx.x;
    const int h = head[b], tq = tail[b], r = rels[b];

    const float eh = psum[(size_t)h  * DIM + d] / fmaxf((float)pcnt[h],  1.f);
    const float et = psum[(size_t)tq * DIM + d] / fmaxf((float)pcnt[tq], 1.f);
    const float diff = eh + rel_embs[r * DIM + d] - et;
    float sq = diff * diff;
    for (int off = 32; off > 0; off >>= 1) sq += __shfl_down(sq, off);
    __shared__ float partial[2];
    if ((threadIdx.x & 63) == 0) partial[threadIdx.x >> 6] = sq;
    __syncthreads();
    if (threadIdx.x == 0) out[b] = -sqrtf(partial[0] + partial[1]);
}

// ---------------------------------------------------------------------------
extern "C" void kernel_launch(void* const* d_in, const int* in_sizes, int n_in,
                              void* d_out, int out_size, void* d_ws, size_t ws_size,
                              hipStream_t stream) {
    const int*   neighbor_idx = (const int*)  d_in[0];
    const int*   rel_id       = (const int*)  d_in[1];
    const float* years        = (const float*)d_in[2];
    const float* months       = (const float*)d_in[3];
    const float* days         = (const float*)d_in[4];
    const int*   pool_src     = (const int*)  d_in[5];
    const int*   pool_dst     = (const int*)  d_in[6];
    const int*   head_pos     = (const int*)  d_in[7];
    const int*   tail_pos     = (const int*)  d_in[8];
    const int*   rels         = (const int*)  d_in[9];
    const float* ent_embs     = (const float*)d_in[10];
    const float* y_freq       = (const float*)d_in[11];
    const float* y_phi        = (const float*)d_in[12];
    const float* y_amp        = (const float*)d_in[13];
    const float* m_freq       = (const float*)d_in[14];
    const float* m_phi        = (const float*)d_in[15];
    const float* m_amp        = (const float*)d_in[16];
    const float* d_freq       = (const float*)d_in[17];
    const float* d_phi        = (const float*)d_in[18];
    const float* d_amp        = (const float*)d_in[19];
    const float* rel_embs     = (const float*)d_in[20];
    const float* W            = (const float*)d_in[21];
    const float* bias         = (const float*)d_in[22];
    const float* gamma        = (const float*)d_in[23];
    const float* beta         = (const float*)d_in[24];

    float* out = (float*)d_out;

    // workspace layout (float units). Zero region (psum..histE) contiguous.
    float* ws = (float*)d_ws;
    size_t off = 0;
    unsigned short* Wfrag = (unsigned short*)(ws + off); off += (size_t)R2 * DIM * DIM / 2;  // 15 MB
    unsigned short* z_s   = (unsigned short*)(ws + off); off += (size_t)N_NBR * DIM / 2;     // 8 MB
    float* psum   = ws + off; off += (size_t)Q_ENT * DIM;  // zero region start (2 MB)
    int* pcnt     = (int*)(ws + off); off += Q_ENT;
    int* hist_rel = (int*)(ws + off); off += R2;
    int* histE    = (int*)(ws + off); off += R2;           // zero region end
    int* ticket_n = (int*)(ws + off); off += N_NBR;
    int* ticket_e = (int*)(ws + off); off += E_EDGE;
    int* offsets  = (int*)(ws + off); off += R2 + 1;
    int* eoff     = (int*)(ws + off); off += R2 + 1;
    int* order    = (int*)(ws + off); off += N_NBR;
    int* rankpack = (int*)(ws + off); off += N_NBR;
    int* epack    = (int*)(ws + off); off += E_EDGE;

    const int nzero  = Q_ENT * DIM + Q_ENT + 2 * R2;   // 529,304 ints
    const int nzero4 = nzero / 4;                      // 132,326 int4
    k_zero<<<(nzero4 + 255) / 256, 256, 0, stream>>>((int*)psum, nzero4);

    k_front<<<R2 + (N_NBR + 255) / 256, 256, 0, stream>>>(
        W, Wfrag, rel_id, pool_src, pool_dst,
        hist_rel, histE, pcnt, ticket_n, ticket_e);

    k_place<<<(N_NBR + 255) / 256, 256, 0, stream>>>(
        rel_id, pool_src, pool_dst, hist_rel, histE,
        ticket_n, ticket_e, offsets, eoff, order, rankpack, epack);

    k_matvec<<<R2, 512, 0, stream>>>(order, offsets, eoff, epack, rankpack,
                                     neighbor_idx,
                                     years, months, days, ent_embs,
                                     y_freq, y_phi, y_amp,
                                     m_freq, m_phi, m_amp,
                                     d_freq, d_phi, d_amp,
                                     Wfrag, bias, gamma, beta,
                                     z_s, psum);

    k_score<<<B_TRI, DIM, 0, stream>>>(head_pos, tail_pos, rels,
                                       psum, pcnt, rel_embs, out);
}

// Round 15
// 74.812 us; speedup vs baseline: 1.0634x; 1.0634x over previous
//
#include <hip/hip_runtime.h>
#include <math.h>

#define NUM_ENT 10000
#define NUM_REL 230
#define R2      460
#define S_DIM   96
#define T_DIM   32
#define DIM     128
#define N_NBR   32768
#define Q_ENT   4096
#define E_EDGE  32768
#define B_TRI   1024
#define BN_EPS  1e-5f
#define CHUNK   64

typedef __attribute__((ext_vector_type(8))) short bf16x8;
typedef __attribute__((ext_vector_type(4))) float f32x4;

// f32 -> bf16 round-to-nearest-even
__device__ __forceinline__ unsigned short f2bf(float f) {
    unsigned int u = __float_as_uint(f);
    u = (u + 0x7FFFu + ((u >> 16) & 1u)) >> 16;
    return (unsigned short)u;
}
__device__ __forceinline__ float bf2f(unsigned short us) {
    return __uint_as_float((unsigned int)us << 16);
}

// X LDS swizzle (ushort units): breaks the 256B row stride for A-frag b128
// reads. XOR bits >=3 keep 4-ushort groups contiguous (8B stores ok).
__device__ __forceinline__ int XIDX(int m, int d) {
    return (m * DIM + d) ^ ((m & 7) << 3);
}

// ---------------------------------------------------------------------------
// K0: zero hist_rel(460)+histE(460)+hist_dst(4096) = 5016 ints (1254 int4)
// ---------------------------------------------------------------------------
__global__ void k_zero(int* __restrict__ p, int n4) {
    int i = blockIdx.x * blockDim.x + threadIdx.x;
    if (i < n4) ((int4*)p)[i] = make_int4(0, 0, 0, 0);
}

// ---------------------------------------------------------------------------
// K1: blocks [0,460): W[r] f32 -> bf16 in per-lane MFMA fragment order.
// blocks [460,588): tickets (rank within bucket) for three orderings:
//   ticket_n[i]: neighbor i within its relation bucket      (hist_rel)
//   ticket_e[i]: edge i within its source-relation bucket   (histE)
//   ticket_d[i]: edge i within its destination bucket       (hist_dst)
// ---------------------------------------------------------------------------
__global__ __launch_bounds__(256, 2) void k_front(
    const float* __restrict__ W, unsigned short* __restrict__ Wfrag,
    const int* __restrict__ rel, const int* __restrict__ psrc,
    const int* __restrict__ pdst,
    int* __restrict__ hist_rel, int* __restrict__ histE,
    int* __restrict__ hist_dst,
    int* __restrict__ ticket_n, int* __restrict__ ticket_e,
    int* __restrict__ ticket_d)
{
    const int t = threadIdx.x;
    if (blockIdx.x >= R2) {
        const int i = (blockIdx.x - R2) * 256 + t;
        if (i < N_NBR) ticket_n[i] = atomicAdd(&hist_rel[rel[i]], 1);
        if (i < E_EDGE) {
            const int s = psrc[i];
            ticket_e[i] = atomicAdd(&histE[rel[s]], 1);
            ticket_d[i] = atomicAdd(&hist_dst[pdst[i]], 1);
        }
        return;
    }
    const int r = blockIdx.x;
    __shared__ float Wl[DIM * DIM];   // 64 KB
    {
        const float4* Wg = (const float4*)(W + (size_t)r * DIM * DIM);
        float4* Wl4 = (float4*)Wl;
        #pragma unroll
        for (int i = 0; i < 16; ++i)
            Wl4[t + i * 256] = Wg[t + i * 256];
    }
    __syncthreads();
    unsigned short* dst = Wfrag + (size_t)r * DIM * DIM;
    #pragma unroll
    for (int it = 0; it < 8; ++it) {
        const int id = t + it * 256;            // 0..2047
        const int lane = id & 63;
        const int h    = (id >> 6) & 1;
        const int wv   = (id >> 7) & 3;
        const int kk   = (id >> 9) & 3;
        const int n  = 32 * wv + 16 * h + (lane & 15);
        const int kb = 32 * kk + 8 * (lane >> 4);
        ushort4 lo, hi;
        lo.x = f2bf(Wl[(kb + 0) * DIM + n]);
        lo.y = f2bf(Wl[(kb + 1) * DIM + n]);
        lo.z = f2bf(Wl[(kb + 2) * DIM + n]);
        lo.w = f2bf(Wl[(kb + 3) * DIM + n]);
        hi.x = f2bf(Wl[(kb + 4) * DIM + n]);
        hi.y = f2bf(Wl[(kb + 5) * DIM + n]);
        hi.z = f2bf(Wl[(kb + 6) * DIM + n]);
        hi.w = f2bf(Wl[(kb + 7) * DIM + n]);
        *(ushort4*)&dst[id * 8]     = lo;
        *(ushort4*)&dst[id * 8 + 4] = hi;
    }
}

// ---------------------------------------------------------------------------
// K2: place. Every block redoes all three scans in LDS (no cross-block
// dependency), then scatters via offset[bucket] + ticket:
//   order[pos] = neighbor index (rel-sorted, for matvec staging)
//   epack[epos] = row | dpos<<15  (edge in rel-order; row = z_s row of its
//                                  source, dpos = dst-sorted slot in eval)
// Block 0 publishes offsets[461], eoff[461], dst_off[4097].
// ---------------------------------------------------------------------------
__global__ __launch_bounds__(256) void k_place(
    const int* __restrict__ rel, const int* __restrict__ psrc,
    const int* __restrict__ pdst,
    const int* __restrict__ hist_rel, const int* __restrict__ histE,
    const int* __restrict__ hist_dst,
    const int* __restrict__ ticket_n, const int* __restrict__ ticket_e,
    const int* __restrict__ ticket_d,
    int* __restrict__ offsets, int* __restrict__ eoff, int* __restrict__ dst_off,
    int* __restrict__ order, int* __restrict__ epack)
{
    __shared__ int hA[512], hE[512], hD[4096], part[256];
    const int t = threadIdx.x;
    const int b = blockIdx.x;

    hA[t]       = (t < R2) ? hist_rel[t] : 0;
    hA[t + 256] = (t + 256 < R2) ? hist_rel[t + 256] : 0;
    hE[t]       = (t < R2) ? histE[t] : 0;
    hE[t + 256] = (t + 256 < R2) ? histE[t + 256] : 0;
    #pragma unroll
    for (int j = 0; j < 16; ++j) hD[t + j * 256] = hist_dst[t + j * 256];
    __syncthreads();

    // ---- scan A (neighbor rel buckets): thread owns bins 2t, 2t+1
    const int a0 = hA[2 * t], a1 = hA[2 * t + 1];
    part[t] = a0 + a1;
    __syncthreads();
    for (int off = 1; off < 256; off <<= 1) {
        int v = (t >= off) ? part[t - off] : 0;
        __syncthreads();
        part[t] += v;
        __syncthreads();
    }
    {
        const int ex = t ? part[t - 1] : 0;
        hA[2 * t] = ex; hA[2 * t + 1] = ex + a0;
        if (b == 0) {
            if (2 * t < R2)     offsets[2 * t]     = ex;
            if (2 * t + 1 < R2) offsets[2 * t + 1] = ex + a0;
            if (t == 255)       offsets[R2]        = part[255];
        }
    }
    __syncthreads();

    // ---- scan E (edge source-relation buckets)
    const int b0 = hE[2 * t], b1 = hE[2 * t + 1];
    part[t] = b0 + b1;
    __syncthreads();
    for (int off = 1; off < 256; off <<= 1) {
        int v = (t >= off) ? part[t - off] : 0;
        __syncthreads();
        part[t] += v;
        __syncthreads();
    }
    {
        const int ex = t ? part[t - 1] : 0;
        hE[2 * t] = ex; hE[2 * t + 1] = ex + b0;
        if (b == 0) {
            if (2 * t < R2)     eoff[2 * t]     = ex;
            if (2 * t + 1 < R2) eoff[2 * t + 1] = ex + b0;
            if (t == 255)       eoff[R2]        = part[255];
        }
    }
    __syncthreads();

    // ---- scan D (edge dst buckets, 4096 bins, 16/thread)
    {
        const int base = t * 16;
        int v[16]; int lsum = 0;
        #pragma unroll
        for (int j = 0; j < 16; ++j) { v[j] = hD[base + j]; lsum += v[j]; }
        part[t] = lsum;
        __syncthreads();
        for (int off = 1; off < 256; off <<= 1) {
            int vv = (t >= off) ? part[t - off] : 0;
            __syncthreads();
            part[t] += vv;
            __syncthreads();
        }
        int run = t ? part[t - 1] : 0;
        #pragma unroll
        for (int j = 0; j < 16; ++j) {
            hD[base + j] = run;
            if (b == 0) dst_off[base + j] = run;
            run += v[j];
        }
        if (b == 0 && t == 255) dst_off[4096] = run;
    }
    __syncthreads();

    // ---- scatter
    const int i = b * 256 + t;
    if (i < N_NBR) {
        order[hA[rel[i]] + ticket_n[i]] = i;
    }
    if (i < E_EDGE) {
        const int s = psrc[i];
        const int row  = hA[rel[s]] + ticket_n[s];       // z_s row of source
        const int epos = hE[rel[s]] + ticket_e[i];       // rel-order slot
        const int dpos = hD[pdst[i]] + ticket_d[i];      // dst-order slot
        epack[epos] = row | (dpos << 15);
    }
}

// ---------------------------------------------------------------------------
// K3: MFMA matvec + BN + FUSED EDGE-VALUE PHASE. One block (512 thr = 8
// waves) per relation; two 64-row chunks in flight (half = wid>>2). After
// the BN fold (scale/shift in LDS), the block walks its rel-sorted edge
// segment, re-reads its own L2-hot bf16 z rows, applies affine+ReLU, and
// writes each edge's value vector to eval[dpos] (dst-sorted, NO atomics).
// ---------------------------------------------------------------------------
__global__ __launch_bounds__(512, 4) void k_matvec(
    const int* __restrict__ order, const int* __restrict__ offsets,
    const int* __restrict__ eoff, const int* __restrict__ epack,
    const int* __restrict__ nbr,
    const float* __restrict__ years, const float* __restrict__ months, const float* __restrict__ days,
    const float* __restrict__ ent,
    const float* __restrict__ yf, const float* __restrict__ yp, const float* __restrict__ ya,
    const float* __restrict__ mf, const float* __restrict__ mp, const float* __restrict__ ma,
    const float* __restrict__ df, const float* __restrict__ dp, const float* __restrict__ da,
    const unsigned short* __restrict__ Wfrag, const float* __restrict__ bias,
    const float* __restrict__ gamma, const float* __restrict__ beta,
    unsigned short* __restrict__ z_s, unsigned short* __restrict__ eval)
{
    const int r     = blockIdx.x;
    const int start = offsets[r];
    const int cnt   = offsets[r + 1] - start;

    __shared__ __align__(16) unsigned short Xl[2][CHUNK * DIM];  // 32 KB
    __shared__ int s_ord[2][CHUNK];
    __shared__ int s_ni[2][CHUNK];
    __shared__ float bnred[8][2][16][2];   // [wid][nt][l15][sum|sq]
    __shared__ float scl[DIM], shf[DIM];

    const int t    = threadIdx.x;
    const int wid  = t >> 6;        // 0..7
    const int half = wid >> 2;      // 0,1 : which chunk of the pair
    const int wv   = wid & 3;       // column group
    const int lane = t & 63;
    const int l15  = lane & 15;
    const int g    = lane >> 4;

    const int nn0 = 32 * wv + l15;
    const int nn1 = nn0 + 16;
    const float bv0 = bias[r * DIM + nn0];
    const float bv1 = bias[r * DIM + nn1];

    float lsum0 = 0.f, lsq0 = 0.f, lsum1 = 0.f, lsq1 = 0.f;
    const unsigned short* Wr = Wfrag + (size_t)r * DIM * DIM;

    for (int cbase = 0; cbase < cnt; cbase += 2 * CHUNK) {
        const int hbase = cbase + half * CHUNK;
        const int mcnt  = min(CHUNK, max(0, cnt - hbase));

        if (t < 2 * CHUNK) {
            const int hh = t >> 6;   // half being staged
            const int m  = t & 63;
            const int gb = cbase + hh * CHUNK;
            int o = -1, ni = 0;
            if (gb + m < cnt) { o = order[start + gb + m]; ni = nbr[o]; }
            s_ord[hh][m] = o;
            s_ni[hh][m]  = ni;
        }
        __syncthreads();

        // ---- gather X for this half (256 threads): 4 thr/row
        if (mcnt > 0) {
            const int lt = t & 255;
            const int m = lt >> 2, s = lt & 3;
            const int ni = s_ni[half][m];
            const bool vm = (m < mcnt);
            #pragma unroll
            for (int kk = 0; kk < 6; ++kk) {
                const int d = 4 * (s + 4 * kk);
                float4 e = *(const float4*)(ent + (size_t)ni * S_DIM + d);
                ushort4 b;
                b.x = vm ? f2bf(e.x) : 0; b.y = vm ? f2bf(e.y) : 0;
                b.z = vm ? f2bf(e.z) : 0; b.w = vm ? f2bf(e.w) : 0;
                *(ushort4*)&Xl[half][XIDX(m, d)] = b;
            }
            const int o = s_ord[half][m] < 0 ? 0 : s_ord[half][m];
            const float yr = years[o], mo = months[o], dy = days[o];
            #pragma unroll
            for (int hh = 0; hh < 2; ++hh) {
                const int j0 = s * 8 + hh * 4;
                const size_t tb = (size_t)ni * T_DIM + j0;
                const float4 vyf = *(const float4*)(yf + tb), vyp = *(const float4*)(yp + tb), vya = *(const float4*)(ya + tb);
                const float4 vmf = *(const float4*)(mf + tb), vmp = *(const float4*)(mp + tb), vma = *(const float4*)(ma + tb);
                const float4 vdf = *(const float4*)(df + tb), vdp = *(const float4*)(dp + tb), vda = *(const float4*)(da + tb);
                ushort4 b;
                #pragma unroll
                for (int j = 0; j < 4; ++j) {
                    const float fy = ((const float*)&vyf)[j] * yr + ((const float*)&vyp)[j];
                    const float fm = ((const float*)&vmf)[j] * mo + ((const float*)&vmp)[j];
                    const float fd = ((const float*)&vdf)[j] * dy + ((const float*)&vdp)[j];
                    float v = ((const float*)&vya)[j] * sinf(fy)
                            + ((const float*)&vma)[j] * sinf(fm)
                            + ((const float*)&vda)[j] * sinf(fd);
                    ((unsigned short*)&b)[j] = vm ? f2bf(v) : 0;
                }
                *(ushort4*)&Xl[half][XIDX(m, S_DIM + j0)] = b;
            }
        }
        __syncthreads();

        // ---- MFMA + epilogue for this half
        if (mcnt > 0) {
            f32x4 acc[4][2];
            #pragma unroll
            for (int i = 0; i < 4; ++i)
                #pragma unroll
                for (int j = 0; j < 2; ++j) acc[i][j] = (f32x4)0.f;

            #pragma unroll
            for (int kk = 0; kk < 4; ++kk) {
                const int k0 = kk * 32;
                bf16x8 a[4];
                #pragma unroll
                for (int mt = 0; mt < 4; ++mt)
                    a[mt] = *(const bf16x8*)&Xl[half][XIDX(16 * mt + l15, k0 + 8 * g)];
                const bf16x8 b0 = *(const bf16x8*)&Wr[(size_t)((kk * 4 + wv) * 2 + 0) * 512 + lane * 8];
                const bf16x8 b1 = *(const bf16x8*)&Wr[(size_t)((kk * 4 + wv) * 2 + 1) * 512 + lane * 8];
                #pragma unroll
                for (int mt = 0; mt < 4; ++mt) {
                    acc[mt][0] = __builtin_amdgcn_mfma_f32_16x16x32_bf16(a[mt], b0, acc[mt][0], 0, 0, 0);
                    acc[mt][1] = __builtin_amdgcn_mfma_f32_16x16x32_bf16(a[mt], b1, acc[mt][1], 0, 0, 0);
                }
            }

            #pragma unroll
            for (int mt = 0; mt < 4; ++mt) {
                #pragma unroll
                for (int reg = 0; reg < 4; ++reg) {
                    const int ml = 16 * mt + 4 * g + reg;
                    if (ml < mcnt) {
                        const float v0 = acc[mt][0][reg] + bv0;
                        const float v1 = acc[mt][1][reg] + bv1;
                        const size_t row = (size_t)(start + hbase + ml) * DIM;
                        z_s[row + nn0] = f2bf(v0);
                        z_s[row + nn1] = f2bf(v1);
                        lsum0 += v0; lsq0 += v0 * v0;
                        lsum1 += v1; lsq1 += v1 * v1;
                    }
                }
            }
        }
        __syncthreads();
    }

    // ---- BN fold: intra-wave (over g), cross-half via LDS -> scl/shf LDS
    lsum0 += __shfl_xor(lsum0, 16); lsum0 += __shfl_xor(lsum0, 32);
    lsq0  += __shfl_xor(lsq0, 16);  lsq0  += __shfl_xor(lsq0, 32);
    lsum1 += __shfl_xor(lsum1, 16); lsum1 += __shfl_xor(lsum1, 32);
    lsq1  += __shfl_xor(lsq1, 16);  lsq1  += __shfl_xor(lsq1, 32);
    if (g == 0) {
        bnred[wid][0][l15][0] = lsum0; bnred[wid][0][l15][1] = lsq0;
        bnred[wid][1][l15][0] = lsum1; bnred[wid][1][l15][1] = lsq1;
    }
    __syncthreads();
    if (half == 0 && g == 0) {
        #pragma unroll
        for (int nt = 0; nt < 2; ++nt) {
            const int col = 32 * wv + 16 * nt + l15;
            const float s = bnred[wid][nt][l15][0] + bnred[wid + 4][nt][l15][0];
            const float q = bnred[wid][nt][l15][1] + bnred[wid + 4][nt][l15][1];
            float sc = 1.f, sh = 0.f;
            if (cnt > 1) {
                const float mean = s / (float)cnt;
                const float var  = fmaxf(q / (float)cnt - mean * mean, 0.f);
                const int gi = r * DIM + col;
                sc = gamma[gi] * rsqrtf(var + BN_EPS);
                sh = beta[gi] - mean * sc;
            }
            scl[col] = sc;
            shf[col] = sh;
        }
    }
    __syncthreads();

    // ---- FUSED EDGE-VALUE phase: z rows L2-hot; plain stores, no atomics.
    {
        const int e0 = eoff[r], e1 = eoff[r + 1];
        const int grp = t >> 7;      // 4 edges concurrently (128 thr each)
        const int d   = t & 127;
        const float psc = scl[d], psh = shf[d];
        for (int e = e0 + grp; e < e1; e += 4) {
            const int pk   = epack[e];
            const int row  = pk & 0x7FFF;
            const int dpos = pk >> 15;
            const float v = fmaxf(bf2f(z_s[(size_t)row * DIM + d]) * psc + psh, 0.f);
            eval[(size_t)dpos * DIM + d] = f2bf(v);
        }
    }
}

// ---------------------------------------------------------------------------
// K4: TransE scoring with on-the-fly pooling: per triple, sum the head's
// and tail's contiguous eval rows (dst-sorted), average, diff, norm.
// ---------------------------------------------------------------------------
__global__ void k_score(const int* __restrict__ head, const int* __restrict__ tail,
                        const int* __restrict__ rels,
                        const unsigned short* __restrict__ eval,
                        const int* __restrict__ dst_off,
                        const float* __restrict__ rel_embs,
                        float* __restrict__ out)
{
    const int b = blockIdx.x;
    const int d = threadIdx.x;
    const int h = head[b], tq = tail[b], r = rels[b];

    const int h0 = dst_off[h],  h1 = dst_off[h + 1];
    const int t0 = dst_off[tq], t1 = dst_off[tq + 1];

    float fh = 0.f;
    for (int e = h0; e < h1; ++e) fh += bf2f(eval[(size_t)e * DIM + d]);
    fh /= (float)max(h1 - h0, 1);

    float ft = 0.f;
    for (int e = t0; e < t1; ++e) ft += bf2f(eval[(size_t)e * DIM + d]);
    ft /= (float)max(t1 - t0, 1);

    const float diff = fh + rel_embs[r * DIM + d] - ft;
    float sq = diff * diff;
    for (int off = 32; off > 0; off >>= 1) sq += __shfl_down(sq, off);
    __shared__ float partial[2];
    if ((threadIdx.x & 63) == 0) partial[threadIdx.x >> 6] = sq;
    __syncthreads();
    if (threadIdx.x == 0) out[b] = -sqrtf(partial[0] + partial[1]);
}

// ---------------------------------------------------------------------------
extern "C" void kernel_launch(void* const* d_in, const int* in_sizes, int n_in,
                              void* d_out, int out_size, void* d_ws, size_t ws_size,
                              hipStream_t stream) {
    const int*   neighbor_idx = (const int*)  d_in[0];
    const int*   rel_id       = (const int*)  d_in[1];
    const float* years        = (const float*)d_in[2];
    const float* months       = (const float*)d_in[3];
    const float* days         = (const float*)d_in[4];
    const int*   pool_src     = (const int*)  d_in[5];
    const int*   pool_dst     = (const int*)  d_in[6];
    const int*   head_pos     = (const int*)  d_in[7];
    const int*   tail_pos     = (const int*)  d_in[8];
    const int*   rels         = (const int*)  d_in[9];
    const float* ent_embs     = (const float*)d_in[10];
    const float* y_freq       = (const float*)d_in[11];
    const float* y_phi        = (const float*)d_in[12];
    const float* y_amp        = (const float*)d_in[13];
    const float* m_freq       = (const float*)d_in[14];
    const float* m_phi        = (const float*)d_in[15];
    const float* m_amp        = (const float*)d_in[16];
    const float* d_freq       = (const float*)d_in[17];
    const float* d_phi        = (const float*)d_in[18];
    const float* d_amp        = (const float*)d_in[19];
    const float* rel_embs     = (const float*)d_in[20];
    const float* W            = (const float*)d_in[21];
    const float* bias         = (const float*)d_in[22];
    const float* gamma        = (const float*)d_in[23];
    const float* beta         = (const float*)d_in[24];

    float* out = (float*)d_out;

    // workspace layout (float units). Zero region (hist_rel..hist_dst)
    // contiguous: 460 + 460 + 4096 = 5016 ints.
    float* ws = (float*)d_ws;
    size_t off = 0;
    unsigned short* Wfrag = (unsigned short*)(ws + off); off += (size_t)R2 * DIM * DIM / 2;  // 15 MB
    unsigned short* z_s   = (unsigned short*)(ws + off); off += (size_t)N_NBR * DIM / 2;     // 8 MB
    unsigned short* eval  = (unsigned short*)(ws + off); off += (size_t)E_EDGE * DIM / 2;    // 8 MB
    int* hist_rel = (int*)(ws + off); off += R2;     // zero region start
    int* histE    = (int*)(ws + off); off += R2;
    int* hist_dst = (int*)(ws + off); off += Q_ENT;  // zero region end
    int* ticket_n = (int*)(ws + off); off += N_NBR;
    int* ticket_e = (int*)(ws + off); off += E_EDGE;
    int* ticket_d = (int*)(ws + off); off += E_EDGE;
    int* offsets  = (int*)(ws + off); off += R2 + 1;
    int* eoff     = (int*)(ws + off); off += R2 + 1;
    int* dst_off  = (int*)(ws + off); off += Q_ENT + 1;
    int* order    = (int*)(ws + off); off += N_NBR;
    int* epack    = (int*)(ws + off); off += E_EDGE;

    const int nzero  = 2 * R2 + Q_ENT;    // 5016 ints
    const int nzero4 = (nzero + 3) / 4;   // 1254 int4
    k_zero<<<(nzero4 + 255) / 256, 256, 0, stream>>>(hist_rel, nzero4);

    k_front<<<R2 + (N_NBR + 255) / 256, 256, 0, stream>>>(
        W, Wfrag, rel_id, pool_src, pool_dst,
        hist_rel, histE, hist_dst, ticket_n, ticket_e, ticket_d);

    k_place<<<(N_NBR + 255) / 256, 256, 0, stream>>>(
        rel_id, pool_src, pool_dst, hist_rel, histE, hist_dst,
        ticket_n, ticket_e, ticket_d,
        offsets, eoff, dst_off, order, epack);

    k_matvec<<<R2, 512, 0, stream>>>(order, offsets, eoff, epack,
                                     neighbor_idx,
                                     years, months, days, ent_embs,
                                     y_freq, y_phi, y_amp,
                                     m_freq, m_phi, m_amp,
                                     d_freq, d_phi, d_amp,
                                     Wfrag, bias, gamma, beta,
                                     z_s, eval);

    k_score<<<B_TRI, DIM, 0, stream>>>(head_pos, tail_pos, rels,
                                       eval, dst_off, rel_embs, out);
}

// Round 16
// 65.746 us; speedup vs baseline: 1.2100x; 1.1379x over previous
//
#include <hip/hip_runtime.h>
#include <math.h>

#define NUM_ENT 10000
#define NUM_REL 230
#define R2      460
#define S_DIM   96
#define T_DIM   32
#define DIM     128
#define N_NBR   32768
#define Q_ENT   4096
#define E_EDGE  32768
#define B_TRI   1024
#define BN_EPS  1e-5f
#define CHUNK   64
#define ZCAP    128        // LDS z-tile rows (spill to global beyond)

typedef __attribute__((ext_vector_type(8))) short bf16x8;
typedef __attribute__((ext_vector_type(4))) float f32x4;

// f32 -> bf16 round-to-nearest-even
__device__ __forceinline__ unsigned short f2bf(float f) {
    unsigned int u = __float_as_uint(f);
    u = (u + 0x7FFFu + ((u >> 16) & 1u)) >> 16;
    return (unsigned short)u;
}
__device__ __forceinline__ float bf2f(unsigned short us) {
    return __uint_as_float((unsigned int)us << 16);
}

// X LDS swizzle (ushort units): breaks the 256B row stride for A-frag b128
// reads. XOR bits >=3 keep 4-ushort groups contiguous (8B stores ok).
__device__ __forceinline__ int XIDX(int m, int d) {
    return (m * DIM + d) ^ ((m & 7) << 3);
}

// ---------------------------------------------------------------------------
// K0: zero hist_rel(460)+hist_dst(4096) = 4556 ints (1139 int4)
// ---------------------------------------------------------------------------
__global__ void k_zero(int* __restrict__ p, int n4) {
    int i = blockIdx.x * blockDim.x + threadIdx.x;
    if (i < n4) ((int4*)p)[i] = make_int4(0, 0, 0, 0);
}

// ---------------------------------------------------------------------------
// K1: blocks [0,460): W[r] f32 -> bf16 in per-lane MFMA fragment order.
//   Wfrag ushort offset: ((kk*4+wv)*2+h)*512 + lane*8 + j holds
//   bf16(W[r][32*kk + 8*(lane>>4) + j][32*wv + 16*h + (lane&15)]).
// blocks [460,588): tickets (rank within bucket):
//   ticket_n[i]: neighbor i within its relation bucket (hist_rel)
//   ticket_d[i]: edge i within its destination bucket  (hist_dst)
// ---------------------------------------------------------------------------
__global__ __launch_bounds__(256, 2) void k_front(
    const float* __restrict__ W, unsigned short* __restrict__ Wfrag,
    const int* __restrict__ rel, const int* __restrict__ pdst,
    int* __restrict__ hist_rel, int* __restrict__ hist_dst,
    int* __restrict__ ticket_n, int* __restrict__ ticket_d)
{
    const int t = threadIdx.x;
    if (blockIdx.x >= R2) {
        const int i = (blockIdx.x - R2) * 256 + t;
        if (i < N_NBR) ticket_n[i] = atomicAdd(&hist_rel[rel[i]], 1);
        if (i < E_EDGE) ticket_d[i] = atomicAdd(&hist_dst[pdst[i]], 1);
        return;
    }
    const int r = blockIdx.x;
    __shared__ float Wl[DIM * DIM];   // 64 KB
    {
        const float4* Wg = (const float4*)(W + (size_t)r * DIM * DIM);
        float4* Wl4 = (float4*)Wl;
        #pragma unroll
        for (int i = 0; i < 16; ++i)
            Wl4[t + i * 256] = Wg[t + i * 256];
    }
    __syncthreads();
    unsigned short* dst = Wfrag + (size_t)r * DIM * DIM;
    #pragma unroll
    for (int it = 0; it < 8; ++it) {
        const int id = t + it * 256;            // 0..2047
        const int lane = id & 63;
        const int h    = (id >> 6) & 1;
        const int wv   = (id >> 7) & 3;
        const int kk   = (id >> 9) & 3;
        const int n  = 32 * wv + 16 * h + (lane & 15);
        const int kb = 32 * kk + 8 * (lane >> 4);
        ushort4 lo, hi;
        lo.x = f2bf(Wl[(kb + 0) * DIM + n]);
        lo.y = f2bf(Wl[(kb + 1) * DIM + n]);
        lo.z = f2bf(Wl[(kb + 2) * DIM + n]);
        lo.w = f2bf(Wl[(kb + 3) * DIM + n]);
        hi.x = f2bf(Wl[(kb + 4) * DIM + n]);
        hi.y = f2bf(Wl[(kb + 5) * DIM + n]);
        hi.z = f2bf(Wl[(kb + 6) * DIM + n]);
        hi.w = f2bf(Wl[(kb + 7) * DIM + n]);
        *(ushort4*)&dst[id * 8]     = lo;
        *(ushort4*)&dst[id * 8 + 4] = hi;
    }
}

// ---------------------------------------------------------------------------
// K2: place. Every block redoes both scans in LDS (no cross-block
// dependency), then scatters via offset[bucket] + ticket:
//   order[pos] = neighbor index (rel-sorted, for matvec staging)
//   drow[dpos] = global z-row of the edge's source (dst-sorted list)
// Block 0 publishes offsets[461] and dst_off[4097].
// ---------------------------------------------------------------------------
__global__ __launch_bounds__(256) void k_place(
    const int* __restrict__ rel, const int* __restrict__ psrc,
    const int* __restrict__ pdst,
    const int* __restrict__ hist_rel, const int* __restrict__ hist_dst,
    const int* __restrict__ ticket_n, const int* __restrict__ ticket_d,
    int* __restrict__ offsets, int* __restrict__ dst_off,
    int* __restrict__ order, int* __restrict__ drow)
{
    __shared__ int hA[512], hD[4096], part[256];
    const int t = threadIdx.x;
    const int b = blockIdx.x;

    hA[t]       = (t < R2) ? hist_rel[t] : 0;
    hA[t + 256] = (t + 256 < R2) ? hist_rel[t + 256] : 0;
    #pragma unroll
    for (int j = 0; j < 16; ++j) hD[t + j * 256] = hist_dst[t + j * 256];
    __syncthreads();

    // ---- scan A (neighbor rel buckets): thread owns bins 2t, 2t+1
    const int a0 = hA[2 * t], a1 = hA[2 * t + 1];
    part[t] = a0 + a1;
    __syncthreads();
    for (int off = 1; off < 256; off <<= 1) {
        int v = (t >= off) ? part[t - off] : 0;
        __syncthreads();
        part[t] += v;
        __syncthreads();
    }
    {
        const int ex = t ? part[t - 1] : 0;
        hA[2 * t] = ex; hA[2 * t + 1] = ex + a0;
        if (b == 0) {
            if (2 * t < R2)     offsets[2 * t]     = ex;
            if (2 * t + 1 < R2) offsets[2 * t + 1] = ex + a0;
            if (t == 255)       offsets[R2]        = part[255];
        }
    }
    __syncthreads();

    // ---- scan D (edge dst buckets, 4096 bins, 16/thread)
    {
        const int base = t * 16;
        int v[16]; int lsum = 0;
        #pragma unroll
        for (int j = 0; j < 16; ++j) { v[j] = hD[base + j]; lsum += v[j]; }
        part[t] = lsum;
        __syncthreads();
        for (int off = 1; off < 256; off <<= 1) {
            int vv = (t >= off) ? part[t - off] : 0;
            __syncthreads();
            part[t] += vv;
            __syncthreads();
        }
        int run = t ? part[t - 1] : 0;
        #pragma unroll
        for (int j = 0; j < 16; ++j) {
            hD[base + j] = run;
            if (b == 0) dst_off[base + j] = run;
            run += v[j];
        }
        if (b == 0 && t == 255) dst_off[4096] = run;
    }
    __syncthreads();

    // ---- scatter
    const int i = b * 256 + t;
    if (i < N_NBR) {
        order[hA[rel[i]] + ticket_n[i]] = i;
    }
    if (i < E_EDGE) {
        const int s = psrc[i];
        const int row  = hA[rel[s]] + ticket_n[s];   // global z-row of source
        const int dpos = hD[pdst[i]] + ticket_d[i];  // dst-sorted slot
        drow[dpos] = row;
    }
}

// ---------------------------------------------------------------------------
// K3: MFMA matvec + BN, z kept in LDS. One block (512 thr = 8 waves) per
// relation; two 64-row chunks in flight (half = wid>>2). MFMA epilogue
// writes bf16 z rows into LDS Zl (rows >= ZCAP spill raw to zf; fixed
// after BN). BN fold -> scl/shf in LDS; final pass applies affine+ReLU and
// writes the FINISHED rows to zf once (vectorized ushort2).
// LDS ~69 KB -> 2 blocks/CU (grid 460 = 1.8/CU, no loss).
// ---------------------------------------------------------------------------
__global__ __launch_bounds__(512, 4) void k_matvec(
    const int* __restrict__ order, const int* __restrict__ offsets,
    const int* __restrict__ nbr,
    const float* __restrict__ years, const float* __restrict__ months, const float* __restrict__ days,
    const float* __restrict__ ent,
    const float* __restrict__ yf, const float* __restrict__ yp, const float* __restrict__ ya,
    const float* __restrict__ mf, const float* __restrict__ mp, const float* __restrict__ ma,
    const float* __restrict__ df, const float* __restrict__ dp, const float* __restrict__ da,
    const unsigned short* __restrict__ Wfrag, const float* __restrict__ bias,
    const float* __restrict__ gamma, const float* __restrict__ beta,
    unsigned short* __restrict__ zf)
{
    const int r     = blockIdx.x;
    const int start = offsets[r];
    const int cnt   = offsets[r + 1] - start;
    if (cnt == 0) return;

    __shared__ __align__(16) unsigned short Xl[2][CHUNK * DIM];  // 32 KB
    __shared__ __align__(16) unsigned short Zl[ZCAP * DIM];      // 32 KB
    __shared__ int s_ord[2][CHUNK];
    __shared__ int s_ni[2][CHUNK];
    __shared__ float bnred[8][2][16][2];   // [wid][nt][l15][sum|sq]
    __shared__ float scl[DIM], shf[DIM];

    const int t    = threadIdx.x;
    const int wid  = t >> 6;        // 0..7
    const int half = wid >> 2;      // 0,1 : which chunk of the pair
    const int wv   = wid & 3;       // column group
    const int lane = t & 63;
    const int l15  = lane & 15;
    const int g    = lane >> 4;

    const int nn0 = 32 * wv + l15;
    const int nn1 = nn0 + 16;
    const float bv0 = bias[r * DIM + nn0];
    const float bv1 = bias[r * DIM + nn1];

    float lsum0 = 0.f, lsq0 = 0.f, lsum1 = 0.f, lsq1 = 0.f;
    const unsigned short* Wr = Wfrag + (size_t)r * DIM * DIM;

    for (int cbase = 0; cbase < cnt; cbase += 2 * CHUNK) {
        const int hbase = cbase + half * CHUNK;
        const int mcnt  = min(CHUNK, max(0, cnt - hbase));

        if (t < 2 * CHUNK) {
            const int hh = t >> 6;   // half being staged
            const int m  = t & 63;
            const int gb = cbase + hh * CHUNK;
            int o = -1, ni = 0;
            if (gb + m < cnt) { o = order[start + gb + m]; ni = nbr[o]; }
            s_ord[hh][m] = o;
            s_ni[hh][m]  = ni;
        }
        __syncthreads();

        // ---- gather X for this half (256 threads): 4 thr/row
        if (mcnt > 0) {
            const int lt = t & 255;
            const int m = lt >> 2, s = lt & 3;
            const int ni = s_ni[half][m];
            const bool vm = (m < mcnt);
            #pragma unroll
            for (int kk = 0; kk < 6; ++kk) {
                const int d = 4 * (s + 4 * kk);
                float4 e = *(const float4*)(ent + (size_t)ni * S_DIM + d);
                ushort4 b;
                b.x = vm ? f2bf(e.x) : 0; b.y = vm ? f2bf(e.y) : 0;
                b.z = vm ? f2bf(e.z) : 0; b.w = vm ? f2bf(e.w) : 0;
                *(ushort4*)&Xl[half][XIDX(m, d)] = b;
            }
            const int o = s_ord[half][m] < 0 ? 0 : s_ord[half][m];
            const float yr = years[o], mo = months[o], dy = days[o];
            #pragma unroll
            for (int hh = 0; hh < 2; ++hh) {
                const int j0 = s * 8 + hh * 4;
                const size_t tb = (size_t)ni * T_DIM + j0;
                const float4 vyf = *(const float4*)(yf + tb), vyp = *(const float4*)(yp + tb), vya = *(const float4*)(ya + tb);
                const float4 vmf = *(const float4*)(mf + tb), vmp = *(const float4*)(mp + tb), vma = *(const float4*)(ma + tb);
                const float4 vdf = *(const float4*)(df + tb), vdp = *(const float4*)(dp + tb), vda = *(const float4*)(da + tb);
                ushort4 b;
                #pragma unroll
                for (int j = 0; j < 4; ++j) {
                    const float fy = ((const float*)&vyf)[j] * yr + ((const float*)&vyp)[j];
                    const float fm = ((const float*)&vmf)[j] * mo + ((const float*)&vmp)[j];
                    const float fd = ((const float*)&vdf)[j] * dy + ((const float*)&vdp)[j];
                    float v = ((const float*)&vya)[j] * sinf(fy)
                            + ((const float*)&vma)[j] * sinf(fm)
                            + ((const float*)&vda)[j] * sinf(fd);
                    ((unsigned short*)&b)[j] = vm ? f2bf(v) : 0;
                }
                *(ushort4*)&Xl[half][XIDX(m, S_DIM + j0)] = b;
            }
        }
        __syncthreads();

        // ---- MFMA + epilogue for this half
        if (mcnt > 0) {
            f32x4 acc[4][2];
            #pragma unroll
            for (int i = 0; i < 4; ++i)
                #pragma unroll
                for (int j = 0; j < 2; ++j) acc[i][j] = (f32x4)0.f;

            #pragma unroll
            for (int kk = 0; kk < 4; ++kk) {
                const int k0 = kk * 32;
                bf16x8 a[4];
                #pragma unroll
                for (int mt = 0; mt < 4; ++mt)
                    a[mt] = *(const bf16x8*)&Xl[half][XIDX(16 * mt + l15, k0 + 8 * g)];
                const bf16x8 b0 = *(const bf16x8*)&Wr[(size_t)((kk * 4 + wv) * 2 + 0) * 512 + lane * 8];
                const bf16x8 b1 = *(const bf16x8*)&Wr[(size_t)((kk * 4 + wv) * 2 + 1) * 512 + lane * 8];
                #pragma unroll
                for (int mt = 0; mt < 4; ++mt) {
                    acc[mt][0] = __builtin_amdgcn_mfma_f32_16x16x32_bf16(a[mt], b0, acc[mt][0], 0, 0, 0);
                    acc[mt][1] = __builtin_amdgcn_mfma_f32_16x16x32_bf16(a[mt], b1, acc[mt][1], 0, 0, 0);
                }
            }

            #pragma unroll
            for (int mt = 0; mt < 4; ++mt) {
                #pragma unroll
                for (int reg = 0; reg < 4; ++reg) {
                    const int ml = 16 * mt + 4 * g + reg;
                    if (ml < mcnt) {
                        const float v0 = acc[mt][0][reg] + bv0;
                        const float v1 = acc[mt][1][reg] + bv1;
                        const int lrow = hbase + ml;
                        if (lrow < ZCAP) {
                            Zl[lrow * DIM + nn0] = f2bf(v0);
                            Zl[lrow * DIM + nn1] = f2bf(v1);
                        } else {   // rare spill: raw z, BN-fixed below
                            const size_t row = (size_t)(start + lrow) * DIM;
                            zf[row + nn0] = f2bf(v0);
                            zf[row + nn1] = f2bf(v1);
                        }
                        lsum0 += v0; lsq0 += v0 * v0;
                        lsum1 += v1; lsq1 += v1 * v1;
                    }
                }
            }
        }
        __syncthreads();
    }

    // ---- BN fold: intra-wave (over g), cross-half via LDS -> scl/shf LDS
    lsum0 += __shfl_xor(lsum0, 16); lsum0 += __shfl_xor(lsum0, 32);
    lsq0  += __shfl_xor(lsq0, 16);  lsq0  += __shfl_xor(lsq0, 32);
    lsum1 += __shfl_xor(lsum1, 16); lsum1 += __shfl_xor(lsum1, 32);
    lsq1  += __shfl_xor(lsq1, 16);  lsq1  += __shfl_xor(lsq1, 32);
    if (g == 0) {
        bnred[wid][0][l15][0] = lsum0; bnred[wid][0][l15][1] = lsq0;
        bnred[wid][1][l15][0] = lsum1; bnred[wid][1][l15][1] = lsq1;
    }
    __syncthreads();
    if (half == 0 && g == 0) {
        #pragma unroll
        for (int nt = 0; nt < 2; ++nt) {
            const int col = 32 * wv + 16 * nt + l15;
            const float s = bnred[wid][nt][l15][0] + bnred[wid + 4][nt][l15][0];
            const float q = bnred[wid][nt][l15][1] + bnred[wid + 4][nt][l15][1];
            float sc = 1.f, sh = 0.f;
            if (cnt > 1) {
                const float mean = s / (float)cnt;
                const float var  = fmaxf(q / (float)cnt - mean * mean, 0.f);
                const int gi = r * DIM + col;
                sc = gamma[gi] * rsqrtf(var + BN_EPS);
                sh = beta[gi] - mean * sc;
            }
            scl[col] = sc;
            shf[col] = sh;
        }
    }
    __syncthreads();

    // ---- BN apply + ReLU, write finished rows once (ushort2/lane)
    {
        const int d2 = (t & 63) * 2;
        const int grp = t >> 6;        // 8 row-groups
        const float sc0 = scl[d2],     sh0 = shf[d2];
        const float sc1 = scl[d2 + 1], sh1 = shf[d2 + 1];
        const int nrows = min(cnt, ZCAP);
        for (int i = grp; i < nrows; i += 8) {
            const ushort2 zz = *(const ushort2*)&Zl[i * DIM + d2];
            ushort2 o;
            o.x = f2bf(fmaxf(bf2f(zz.x) * sc0 + sh0, 0.f));
            o.y = f2bf(fmaxf(bf2f(zz.y) * sc1 + sh1, 0.f));
            *(ushort2*)&zf[(size_t)(start + i) * DIM + d2] = o;
        }
        // rare spill fix: re-read raw rows, apply BN+ReLU in place
        for (int i = ZCAP + grp; i < cnt; i += 8) {
            const size_t base = (size_t)(start + i) * DIM + d2;
            const ushort2 zz = *(const ushort2*)&zf[base];
            ushort2 o;
            o.x = f2bf(fmaxf(bf2f(zz.x) * sc0 + sh0, 0.f));
            o.y = f2bf(fmaxf(bf2f(zz.y) * sc1 + sh1, 0.f));
            *(ushort2*)&zf[base] = o;
        }
    }
}

// ---------------------------------------------------------------------------
// K4: TransE scoring with on-the-fly pooling. ONE WAVE per triple: lane
// owns 2 dims (ushort2 zf reads, float2 rel_embs), full reduce via shfl.
// ---------------------------------------------------------------------------
__global__ void k_score(const int* __restrict__ head, const int* __restrict__ tail,
                        const int* __restrict__ rels,
                        const unsigned short* __restrict__ zf,
                        const int* __restrict__ drow, const int* __restrict__ dst_off,
                        const float* __restrict__ rel_embs,
                        float* __restrict__ out)
{
    const int b = blockIdx.x;
    const int t = threadIdx.x;   // 0..63
    const int d2 = t * 2;
    const int h = head[b], tq = tail[b], r = rels[b];

    const int h0 = dst_off[h],  h1 = dst_off[h + 1];
    const int t0 = dst_off[tq], t1 = dst_off[tq + 1];

    float fh0 = 0.f, fh1 = 0.f;
    for (int e = h0; e < h1; ++e) {
        const ushort2 v = *(const ushort2*)&zf[(size_t)drow[e] * DIM + d2];
        fh0 += bf2f(v.x); fh1 += bf2f(v.y);
    }
    const float hn = 1.f / (float)max(h1 - h0, 1);
    fh0 *= hn; fh1 *= hn;

    float ft0 = 0.f, ft1 = 0.f;
    for (int e = t0; e < t1; ++e) {
        const ushort2 v = *(const ushort2*)&zf[(size_t)drow[e] * DIM + d2];
        ft0 += bf2f(v.x); ft1 += bf2f(v.y);
    }
    const float tn = 1.f / (float)max(t1 - t0, 1);
    ft0 *= tn; ft1 *= tn;

    const float2 re = *(const float2*)&rel_embs[r * DIM + d2];
    const float d0 = fh0 + re.x - ft0;
    const float d1 = fh1 + re.y - ft1;
    float sq = d0 * d0 + d1 * d1;
    for (int off = 32; off > 0; off >>= 1) sq += __shfl_down(sq, off);
    if (t == 0) out[b] = -sqrtf(sq);
}

// ---------------------------------------------------------------------------
extern "C" void kernel_launch(void* const* d_in, const int* in_sizes, int n_in,
                              void* d_out, int out_size, void* d_ws, size_t ws_size,
                              hipStream_t stream) {
    const int*   neighbor_idx = (const int*)  d_in[0];
    const int*   rel_id       = (const int*)  d_in[1];
    const float* years        = (const float*)d_in[2];
    const float* months       = (const float*)d_in[3];
    const float* days         = (const float*)d_in[4];
    const int*   pool_src     = (const int*)  d_in[5];
    const int*   pool_dst     = (const int*)  d_in[6];
    const int*   head_pos     = (const int*)  d_in[7];
    const int*   tail_pos     = (const int*)  d_in[8];
    const int*   rels         = (const int*)  d_in[9];
    const float* ent_embs     = (const float*)d_in[10];
    const float* y_freq       = (const float*)d_in[11];
    const float* y_phi        = (const float*)d_in[12];
    const float* y_amp        = (const float*)d_in[13];
    const float* m_freq       = (const float*)d_in[14];
    const float* m_phi        = (const float*)d_in[15];
    const float* m_amp        = (const float*)d_in[16];
    const float* d_freq       = (const float*)d_in[17];
    const float* d_phi        = (const float*)d_in[18];
    const float* d_amp        = (const float*)d_in[19];
    const float* rel_embs     = (const float*)d_in[20];
    const float* W            = (const float*)d_in[21];
    const float* bias         = (const float*)d_in[22];
    const float* gamma        = (const float*)d_in[23];
    const float* beta         = (const float*)d_in[24];

    float* out = (float*)d_out;

    // workspace layout (float units). Zero region (hist_rel..hist_dst)
    // contiguous: 460 + 4096 = 4556 ints.
    float* ws = (float*)d_ws;
    size_t off = 0;
    unsigned short* Wfrag = (unsigned short*)(ws + off); off += (size_t)R2 * DIM * DIM / 2;  // 15 MB
    unsigned short* zf    = (unsigned short*)(ws + off); off += (size_t)N_NBR * DIM / 2;     // 8 MB
    int* hist_rel = (int*)(ws + off); off += R2;     // zero region start
    int* hist_dst = (int*)(ws + off); off += Q_ENT;  // zero region end
    int* ticket_n = (int*)(ws + off); off += N_NBR;
    int* ticket_d = (int*)(ws + off); off += E_EDGE;
    int* offsets  = (int*)(ws + off); off += R2 + 1;
    int* dst_off  = (int*)(ws + off); off += Q_ENT + 1;
    int* order    = (int*)(ws + off); off += N_NBR;
    int* drow     = (int*)(ws + off); off += E_EDGE;

    const int nzero  = R2 + Q_ENT;        // 4556 ints
    const int nzero4 = (nzero + 3) / 4;   // 1139 int4
    k_zero<<<(nzero4 + 255) / 256, 256, 0, stream>>>(hist_rel, nzero4);

    k_front<<<R2 + (N_NBR + 255) / 256, 256, 0, stream>>>(
        W, Wfrag, rel_id, pool_dst,
        hist_rel, hist_dst, ticket_n, ticket_d);

    k_place<<<(N_NBR + 255) / 256, 256, 0, stream>>>(
        rel_id, pool_src, pool_dst, hist_rel, hist_dst,
        ticket_n, ticket_d, offsets, dst_off, order, drow);

    k_matvec<<<R2, 512, 0, stream>>>(order, offsets,
                                     neighbor_idx,
                                     years, months, days, ent_embs,
                                     y_freq, y_phi, y_amp,
                                     m_freq, m_phi, m_amp,
                                     d_freq, d_phi, d_amp,
                                     Wfrag, bias, gamma, beta,
                                     zf);

    k_score<<<B_TRI, 64, 0, stream>>>(head_pos, tail_pos, rels,
                                      zf, drow, dst_off, rel_embs, out);
}

// Round 17
// 65.244 us; speedup vs baseline: 1.2193x; 1.0077x over previous
//
#include <hip/hip_runtime.h>
#include <math.h>

#define NUM_ENT 10000
#define NUM_REL 230
#define R2      460
#define S_DIM   96
#define T_DIM   32
#define DIM     128
#define N_NBR   32768
#define Q_ENT   4096
#define E_EDGE  32768
#define B_TRI   1024
#define BN_EPS  1e-5f
#define CHUNK   64
#define ZCAP    128        // LDS z-tile rows (spill to global beyond)

typedef __attribute__((ext_vector_type(8))) short bf16x8;
typedef __attribute__((ext_vector_type(4))) float f32x4;

// f32 -> bf16 round-to-nearest-even
__device__ __forceinline__ unsigned short f2bf(float f) {
    unsigned int u = __float_as_uint(f);
    u = (u + 0x7FFFu + ((u >> 16) & 1u)) >> 16;
    return (unsigned short)u;
}
__device__ __forceinline__ float bf2f(unsigned short us) {
    return __uint_as_float((unsigned int)us << 16);
}

// X LDS swizzle (ushort units): breaks the 256B row stride for A-frag b128
// reads. XOR bits >=3 keep 4-ushort groups contiguous (8B stores ok).
__device__ __forceinline__ int XIDX(int m, int d) {
    return (m * DIM + d) ^ ((m & 7) << 3);
}

// ---------------------------------------------------------------------------
// K0: zero hist_rel(460)+hist_dst(4096) = 4556 ints (1139 int4)
// ---------------------------------------------------------------------------
__global__ void k_zero(int* __restrict__ p, int n4) {
    int i = blockIdx.x * blockDim.x + threadIdx.x;
    if (i < n4) ((int4*)p)[i] = make_int4(0, 0, 0, 0);
}

// ---------------------------------------------------------------------------
// K1: blocks [0,460): W[r] f32 -> bf16 in per-lane MFMA fragment order.
//   Wfrag ushort offset: ((kk*4+wv)*2+h)*512 + lane*8 + j holds
//   bf16(W[r][32*kk + 8*(lane>>4) + j][32*wv + 16*h + (lane&15)]).
// blocks [460,588): tickets (rank within bucket):
//   ticket_n[i]: neighbor i within its relation bucket (hist_rel)
//   ticket_d[i]: edge i within its destination bucket  (hist_dst)
// ---------------------------------------------------------------------------
__global__ __launch_bounds__(256, 2) void k_front(
    const float* __restrict__ W, unsigned short* __restrict__ Wfrag,
    const int* __restrict__ rel, const int* __restrict__ pdst,
    int* __restrict__ hist_rel, int* __restrict__ hist_dst,
    int* __restrict__ ticket_n, int* __restrict__ ticket_d)
{
    const int t = threadIdx.x;
    if (blockIdx.x >= R2) {
        const int i = (blockIdx.x - R2) * 256 + t;
        if (i < N_NBR) ticket_n[i] = atomicAdd(&hist_rel[rel[i]], 1);
        if (i < E_EDGE) ticket_d[i] = atomicAdd(&hist_dst[pdst[i]], 1);
        return;
    }
    const int r = blockIdx.x;
    __shared__ float Wl[DIM * DIM];   // 64 KB
    {
        const float4* Wg = (const float4*)(W + (size_t)r * DIM * DIM);
        float4* Wl4 = (float4*)Wl;
        #pragma unroll
        for (int i = 0; i < 16; ++i)
            Wl4[t + i * 256] = Wg[t + i * 256];
    }
    __syncthreads();
    unsigned short* dst = Wfrag + (size_t)r * DIM * DIM;
    #pragma unroll
    for (int it = 0; it < 8; ++it) {
        const int id = t + it * 256;            // 0..2047
        const int lane = id & 63;
        const int h    = (id >> 6) & 1;
        const int wv   = (id >> 7) & 3;
        const int kk   = (id >> 9) & 3;
        const int n  = 32 * wv + 16 * h + (lane & 15);
        const int kb = 32 * kk + 8 * (lane >> 4);
        ushort4 lo, hi;
        lo.x = f2bf(Wl[(kb + 0) * DIM + n]);
        lo.y = f2bf(Wl[(kb + 1) * DIM + n]);
        lo.z = f2bf(Wl[(kb + 2) * DIM + n]);
        lo.w = f2bf(Wl[(kb + 3) * DIM + n]);
        hi.x = f2bf(Wl[(kb + 4) * DIM + n]);
        hi.y = f2bf(Wl[(kb + 5) * DIM + n]);
        hi.z = f2bf(Wl[(kb + 6) * DIM + n]);
        hi.w = f2bf(Wl[(kb + 7) * DIM + n]);
        *(ushort4*)&dst[id * 8]     = lo;
        *(ushort4*)&dst[id * 8 + 4] = hi;
    }
}

// ---------------------------------------------------------------------------
// K2: place. Every block redoes both scans in LDS (no cross-block
// dependency), then scatters via offset[bucket] + ticket:
//   order[pos] = neighbor index (rel-sorted, for matvec staging)
//   drow[dpos] = global z-row of the edge's source (dst-sorted list)
// Block 0 publishes offsets[461] and dst_off[4097].
// ---------------------------------------------------------------------------
__global__ __launch_bounds__(256) void k_place(
    const int* __restrict__ rel, const int* __restrict__ psrc,
    const int* __restrict__ pdst,
    const int* __restrict__ hist_rel, const int* __restrict__ hist_dst,
    const int* __restrict__ ticket_n, const int* __restrict__ ticket_d,
    int* __restrict__ offsets, int* __restrict__ dst_off,
    int* __restrict__ order, int* __restrict__ drow)
{
    __shared__ int hA[512], hD[4096], part[256];
    const int t = threadIdx.x;
    const int b = blockIdx.x;

    hA[t]       = (t < R2) ? hist_rel[t] : 0;
    hA[t + 256] = (t + 256 < R2) ? hist_rel[t + 256] : 0;
    #pragma unroll
    for (int j = 0; j < 16; ++j) hD[t + j * 256] = hist_dst[t + j * 256];
    __syncthreads();

    // ---- scan A (neighbor rel buckets): thread owns bins 2t, 2t+1
    const int a0 = hA[2 * t], a1 = hA[2 * t + 1];
    part[t] = a0 + a1;
    __syncthreads();
    for (int off = 1; off < 256; off <<= 1) {
        int v = (t >= off) ? part[t - off] : 0;
        __syncthreads();
        part[t] += v;
        __syncthreads();
    }
    {
        const int ex = t ? part[t - 1] : 0;
        hA[2 * t] = ex; hA[2 * t + 1] = ex + a0;
        if (b == 0) {
            if (2 * t < R2)     offsets[2 * t]     = ex;
            if (2 * t + 1 < R2) offsets[2 * t + 1] = ex + a0;
            if (t == 255)       offsets[R2]        = part[255];
        }
    }
    __syncthreads();

    // ---- scan D (edge dst buckets, 4096 bins, 16/thread)
    {
        const int base = t * 16;
        int v[16]; int lsum = 0;
        #pragma unroll
        for (int j = 0; j < 16; ++j) { v[j] = hD[base + j]; lsum += v[j]; }
        part[t] = lsum;
        __syncthreads();
        for (int off = 1; off < 256; off <<= 1) {
            int vv = (t >= off) ? part[t - off] : 0;
            __syncthreads();
            part[t] += vv;
            __syncthreads();
        }
        int run = t ? part[t - 1] : 0;
        #pragma unroll
        for (int j = 0; j < 16; ++j) {
            hD[base + j] = run;
            if (b == 0) dst_off[base + j] = run;
            run += v[j];
        }
        if (b == 0 && t == 255) dst_off[4096] = run;
    }
    __syncthreads();

    // ---- scatter
    const int i = b * 256 + t;
    if (i < N_NBR) {
        order[hA[rel[i]] + ticket_n[i]] = i;
    }
    if (i < E_EDGE) {
        const int s = psrc[i];
        const int row  = hA[rel[s]] + ticket_n[s];   // global z-row of source
        const int dpos = hD[pdst[i]] + ticket_d[i];  // dst-sorted slot
        drow[dpos] = row;
    }
}

// ---------------------------------------------------------------------------
// K3: MFMA matvec + BN, z kept in LDS. One block (512 thr = 8 waves) per
// relation; two 64-row chunks in flight (half = wid>>2). MFMA epilogue
// writes bf16 z rows into LDS Zl (rows >= ZCAP spill raw to zf; fixed
// after BN). BN fold -> scl/shf in LDS; final pass applies affine+ReLU and
// writes the FINISHED rows to zf once (vectorized ushort2).
// LDS ~69 KB -> 2 blocks/CU (grid 460 = 1.8/CU, no loss).
// ---------------------------------------------------------------------------
__global__ __launch_bounds__(512, 4) void k_matvec(
    const int* __restrict__ order, const int* __restrict__ offsets,
    const int* __restrict__ nbr,
    const float* __restrict__ years, const float* __restrict__ months, const float* __restrict__ days,
    const float* __restrict__ ent,
    const float* __restrict__ yf, const float* __restrict__ yp, const float* __restrict__ ya,
    const float* __restrict__ mf, const float* __restrict__ mp, const float* __restrict__ ma,
    const float* __restrict__ df, const float* __restrict__ dp, const float* __restrict__ da,
    const unsigned short* __restrict__ Wfrag, const float* __restrict__ bias,
    const float* __restrict__ gamma, const float* __restrict__ beta,
    unsigned short* __restrict__ zf)
{
    const int r     = blockIdx.x;
    const int start = offsets[r];
    const int cnt   = offsets[r + 1] - start;
    if (cnt == 0) return;

    __shared__ __align__(16) unsigned short Xl[2][CHUNK * DIM];  // 32 KB
    __shared__ __align__(16) unsigned short Zl[ZCAP * DIM];      // 32 KB
    __shared__ int s_ord[2][CHUNK];
    __shared__ int s_ni[2][CHUNK];
    __shared__ float bnred[8][2][16][2];   // [wid][nt][l15][sum|sq]
    __shared__ float scl[DIM], shf[DIM];

    const int t    = threadIdx.x;
    const int wid  = t >> 6;        // 0..7
    const int half = wid >> 2;      // 0,1 : which chunk of the pair
    const int wv   = wid & 3;       // column group
    const int lane = t & 63;
    const int l15  = lane & 15;
    const int g    = lane >> 4;

    const int nn0 = 32 * wv + l15;
    const int nn1 = nn0 + 16;
    const float bv0 = bias[r * DIM + nn0];
    const float bv1 = bias[r * DIM + nn1];

    float lsum0 = 0.f, lsq0 = 0.f, lsum1 = 0.f, lsq1 = 0.f;
    const unsigned short* Wr = Wfrag + (size_t)r * DIM * DIM;

    for (int cbase = 0; cbase < cnt; cbase += 2 * CHUNK) {
        const int hbase = cbase + half * CHUNK;
        const int mcnt  = min(CHUNK, max(0, cnt - hbase));

        if (t < 2 * CHUNK) {
            const int hh = t >> 6;   // half being staged
            const int m  = t & 63;
            const int gb = cbase + hh * CHUNK;
            int o = -1, ni = 0;
            if (gb + m < cnt) { o = order[start + gb + m]; ni = nbr[o]; }
            s_ord[hh][m] = o;
            s_ni[hh][m]  = ni;
        }
        __syncthreads();

        // ---- gather X for this half (256 threads): 4 thr/row
        if (mcnt > 0) {
            const int lt = t & 255;
            const int m = lt >> 2, s = lt & 3;
            const int ni = s_ni[half][m];
            const bool vm = (m < mcnt);
            #pragma unroll
            for (int kk = 0; kk < 6; ++kk) {
                const int d = 4 * (s + 4 * kk);
                float4 e = *(const float4*)(ent + (size_t)ni * S_DIM + d);
                ushort4 b;
                b.x = vm ? f2bf(e.x) : 0; b.y = vm ? f2bf(e.y) : 0;
                b.z = vm ? f2bf(e.z) : 0; b.w = vm ? f2bf(e.w) : 0;
                *(ushort4*)&Xl[half][XIDX(m, d)] = b;
            }
            const int o = s_ord[half][m] < 0 ? 0 : s_ord[half][m];
            const float yr = years[o], mo = months[o], dy = days[o];
            #pragma unroll
            for (int hh = 0; hh < 2; ++hh) {
                const int j0 = s * 8 + hh * 4;
                const size_t tb = (size_t)ni * T_DIM + j0;
                const float4 vyf = *(const float4*)(yf + tb), vyp = *(const float4*)(yp + tb), vya = *(const float4*)(ya + tb);
                const float4 vmf = *(const float4*)(mf + tb), vmp = *(const float4*)(mp + tb), vma = *(const float4*)(ma + tb);
                const float4 vdf = *(const float4*)(df + tb), vdp = *(const float4*)(dp + tb), vda = *(const float4*)(da + tb);
                ushort4 b;
                #pragma unroll
                for (int j = 0; j < 4; ++j) {
                    const float fy = ((const float*)&vyf)[j] * yr + ((const float*)&vyp)[j];
                    const float fm = ((const float*)&vmf)[j] * mo + ((const float*)&vmp)[j];
                    const float fd = ((const float*)&vdf)[j] * dy + ((const float*)&vdp)[j];
                    float v = ((const float*)&vya)[j] * sinf(fy)
                            + ((const float*)&vma)[j] * sinf(fm)
                            + ((const float*)&vda)[j] * sinf(fd);
                    ((unsigned short*)&b)[j] = vm ? f2bf(v) : 0;
                }
                *(ushort4*)&Xl[half][XIDX(m, S_DIM + j0)] = b;
            }
        }
        __syncthreads();

        // ---- MFMA + epilogue for this half
        if (mcnt > 0) {
            f32x4 acc[4][2];
            #pragma unroll
            for (int i = 0; i < 4; ++i)
                #pragma unroll
                for (int j = 0; j < 2; ++j) acc[i][j] = (f32x4)0.f;

            #pragma unroll
            for (int kk = 0; kk < 4; ++kk) {
                const int k0 = kk * 32;
                bf16x8 a[4];
                #pragma unroll
                for (int mt = 0; mt < 4; ++mt)
                    a[mt] = *(const bf16x8*)&Xl[half][XIDX(16 * mt + l15, k0 + 8 * g)];
                const bf16x8 b0 = *(const bf16x8*)&Wr[(size_t)((kk * 4 + wv) * 2 + 0) * 512 + lane * 8];
                const bf16x8 b1 = *(const bf16x8*)&Wr[(size_t)((kk * 4 + wv) * 2 + 1) * 512 + lane * 8];
                #pragma unroll
                for (int mt = 0; mt < 4; ++mt) {
                    acc[mt][0] = __builtin_amdgcn_mfma_f32_16x16x32_bf16(a[mt], b0, acc[mt][0], 0, 0, 0);
                    acc[mt][1] = __builtin_amdgcn_mfma_f32_16x16x32_bf16(a[mt], b1, acc[mt][1], 0, 0, 0);
                }
            }

            #pragma unroll
            for (int mt = 0; mt < 4; ++mt) {
                #pragma unroll
                for (int reg = 0; reg < 4; ++reg) {
                    const int ml = 16 * mt + 4 * g + reg;
                    if (ml < mcnt) {
                        const float v0 = acc[mt][0][reg] + bv0;
                        const float v1 = acc[mt][1][reg] + bv1;
                        const int lrow = hbase + ml;
                        if (lrow < ZCAP) {
                            Zl[lrow * DIM + nn0] = f2bf(v0);
                            Zl[lrow * DIM + nn1] = f2bf(v1);
                        } else {   // rare spill: raw z, BN-fixed below
                            const size_t row = (size_t)(start + lrow) * DIM;
                            zf[row + nn0] = f2bf(v0);
                            zf[row + nn1] = f2bf(v1);
                        }
                        lsum0 += v0; lsq0 += v0 * v0;
                        lsum1 += v1; lsq1 += v1 * v1;
                    }
                }
            }
        }
        __syncthreads();
    }

    // ---- BN fold: intra-wave (over g), cross-half via LDS -> scl/shf LDS
    lsum0 += __shfl_xor(lsum0, 16); lsum0 += __shfl_xor(lsum0, 32);
    lsq0  += __shfl_xor(lsq0, 16);  lsq0  += __shfl_xor(lsq0, 32);
    lsum1 += __shfl_xor(lsum1, 16); lsum1 += __shfl_xor(lsum1, 32);
    lsq1  += __shfl_xor(lsq1, 16);  lsq1  += __shfl_xor(lsq1, 32);
    if (g == 0) {
        bnred[wid][0][l15][0] = lsum0; bnred[wid][0][l15][1] = lsq0;
        bnred[wid][1][l15][0] = lsum1; bnred[wid][1][l15][1] = lsq1;
    }
    __syncthreads();
    if (half == 0 && g == 0) {
        #pragma unroll
        for (int nt = 0; nt < 2; ++nt) {
            const int col = 32 * wv + 16 * nt + l15;
            const float s = bnred[wid][nt][l15][0] + bnred[wid + 4][nt][l15][0];
            const float q = bnred[wid][nt][l15][1] + bnred[wid + 4][nt][l15][1];
            float sc = 1.f, sh = 0.f;
            if (cnt > 1) {
                const float mean = s / (float)cnt;
                const float var  = fmaxf(q / (float)cnt - mean * mean, 0.f);
                const int gi = r * DIM + col;
                sc = gamma[gi] * rsqrtf(var + BN_EPS);
                sh = beta[gi] - mean * sc;
            }
            scl[col] = sc;
            shf[col] = sh;
        }
    }
    __syncthreads();

    // ---- BN apply + ReLU, write finished rows once (ushort2/lane)
    {
        const int d2 = (t & 63) * 2;
        const int grp = t >> 6;        // 8 row-groups
        const float sc0 = scl[d2],     sh0 = shf[d2];
        const float sc1 = scl[d2 + 1], sh1 = shf[d2 + 1];
        const int nrows = min(cnt, ZCAP);
        for (int i = grp; i < nrows; i += 8) {
            const ushort2 zz = *(const ushort2*)&Zl[i * DIM + d2];
            ushort2 o;
            o.x = f2bf(fmaxf(bf2f(zz.x) * sc0 + sh0, 0.f));
            o.y = f2bf(fmaxf(bf2f(zz.y) * sc1 + sh1, 0.f));
            *(ushort2*)&zf[(size_t)(start + i) * DIM + d2] = o;
        }
        // rare spill fix: re-read raw rows, apply BN+ReLU in place
        for (int i = ZCAP + grp; i < cnt; i += 8) {
            const size_t base = (size_t)(start + i) * DIM + d2;
            const ushort2 zz = *(const ushort2*)&zf[base];
            ushort2 o;
            o.x = f2bf(fmaxf(bf2f(zz.x) * sc0 + sh0, 0.f));
            o.y = f2bf(fmaxf(bf2f(zz.y) * sc1 + sh1, 0.f));
            *(ushort2*)&zf[base] = o;
        }
    }
}

// ---------------------------------------------------------------------------
// K4: TransE scoring with on-the-fly pooling. ONE WAVE per triple: lane
// owns 2 dims (ushort2 zf reads, float2 rel_embs), full reduce via shfl.
// ---------------------------------------------------------------------------
__global__ void k_score(const int* __restrict__ head, const int* __restrict__ tail,
                        const int* __restrict__ rels,
                        const unsigned short* __restrict__ zf,
                        const int* __restrict__ drow, const int* __restrict__ dst_off,
                        const float* __restrict__ rel_embs,
                        float* __restrict__ out)
{
    const int b = blockIdx.x;
    const int t = threadIdx.x;   // 0..63
    const int d2 = t * 2;
    const int h = head[b], tq = tail[b], r = rels[b];

    const int h0 = dst_off[h],  h1 = dst_off[h + 1];
    const int t0 = dst_off[tq], t1 = dst_off[tq + 1];

    float fh0 = 0.f, fh1 = 0.f;
    for (int e = h0; e < h1; ++e) {
        const ushort2 v = *(const ushort2*)&zf[(size_t)drow[e] * DIM + d2];
        fh0 += bf2f(v.x); fh1 += bf2f(v.y);
    }
    const float hn = 1.f / (float)max(h1 - h0, 1);
    fh0 *= hn; fh1 *= hn;

    float ft0 = 0.f, ft1 = 0.f;
    for (int e = t0; e < t1; ++e) {
        const ushort2 v = *(const ushort2*)&zf[(size_t)drow[e] * DIM + d2];
        ft0 += bf2f(v.x); ft1 += bf2f(v.y);
    }
    const float tn = 1.f / (float)max(t1 - t0, 1);
    ft0 *= tn; ft1 *= tn;

    const float2 re = *(const float2*)&rel_embs[r * DIM + d2];
    const float d0 = fh0 + re.x - ft0;
    const float d1 = fh1 + re.y - ft1;
    float sq = d0 * d0 + d1 * d1;
    for (int off = 32; off > 0; off >>= 1) sq += __shfl_down(sq, off);
    if (t == 0) out[b] = -sqrtf(sq);
}

// ---------------------------------------------------------------------------
extern "C" void kernel_launch(void* const* d_in, const int* in_sizes, int n_in,
                              void* d_out, int out_size, void* d_ws, size_t ws_size,
                              hipStream_t stream) {
    const int*   neighbor_idx = (const int*)  d_in[0];
    const int*   rel_id       = (const int*)  d_in[1];
    const float* years        = (const float*)d_in[2];
    const float* months       = (const float*)d_in[3];
    const float* days         = (const float*)d_in[4];
    const int*   pool_src     = (const int*)  d_in[5];
    const int*   pool_dst     = (const int*)  d_in[6];
    const int*   head_pos     = (const int*)  d_in[7];
    const int*   tail_pos     = (const int*)  d_in[8];
    const int*   rels         = (const int*)  d_in[9];
    const float* ent_embs     = (const float*)d_in[10];
    const float* y_freq       = (const float*)d_in[11];
    const float* y_phi        = (const float*)d_in[12];
    const float* y_amp        = (const float*)d_in[13];
    const float* m_freq       = (const float*)d_in[14];
    const float* m_phi        = (const float*)d_in[15];
    const float* m_amp        = (const float*)d_in[16];
    const float* d_freq       = (const float*)d_in[17];
    const float* d_phi        = (const float*)d_in[18];
    const float* d_amp        = (const float*)d_in[19];
    const float* rel_embs     = (const float*)d_in[20];
    const float* W            = (const float*)d_in[21];
    const float* bias         = (const float*)d_in[22];
    const float* gamma        = (const float*)d_in[23];
    const float* beta         = (const float*)d_in[24];

    float* out = (float*)d_out;

    // workspace layout (float units). Zero region (hist_rel..hist_dst)
    // contiguous: 460 + 4096 = 4556 ints.
    float* ws = (float*)d_ws;
    size_t off = 0;
    unsigned short* Wfrag = (unsigned short*)(ws + off); off += (size_t)R2 * DIM * DIM / 2;  // 15 MB
    unsigned short* zf    = (unsigned short*)(ws + off); off += (size_t)N_NBR * DIM / 2;     // 8 MB
    int* hist_rel = (int*)(ws + off); off += R2;     // zero region start
    int* hist_dst = (int*)(ws + off); off += Q_ENT;  // zero region end
    int* ticket_n = (int*)(ws + off); off += N_NBR;
    int* ticket_d = (int*)(ws + off); off += E_EDGE;
    int* offsets  = (int*)(ws + off); off += R2 + 1;
    int* dst_off  = (int*)(ws + off); off += Q_ENT + 1;
    int* order    = (int*)(ws + off); off += N_NBR;
    int* drow     = (int*)(ws + off); off += E_EDGE;

    const int nzero  = R2 + Q_ENT;        // 4556 ints
    const int nzero4 = (nzero + 3) / 4;   // 1139 int4
    k_zero<<<(nzero4 + 255) / 256, 256, 0, stream>>>(hist_rel, nzero4);

    k_front<<<R2 + (N_NBR + 255) / 256, 256, 0, stream>>>(
        W, Wfrag, rel_id, pool_dst,
        hist_rel, hist_dst, ticket_n, ticket_d);

    k_place<<<(N_NBR + 255) / 256, 256, 0, stream>>>(
        rel_id, pool_src, pool_dst, hist_rel, hist_dst,
        ticket_n, ticket_d, offsets, dst_off, order, drow);

    k_matvec<<<R2, 512, 0, stream>>>(order, offsets,
                                     neighbor_idx,
                                     years, months, days, ent_embs,
                                     y_freq, y_phi, y_amp,
                                     m_freq, m_phi, m_amp,
                                     d_freq, d_phi, d_amp,
                                     Wfrag, bias, gamma, beta,
                                     zf);

    k_score<<<B_TRI, 64, 0, stream>>>(head_pos, tail_pos, rels,
                                      zf, drow, dst_off, rel_embs, out);
}